// Round 4
// baseline (78.134 us; speedup 1.0000x reference)
//
#include <hip/hip_runtime.h>
#include <math.h>

// Chamfer distance via MFMA, fp16 quantized / fp32 accumulate.
// K-packing: A_row = (-2ax,-2ay,-2az, 1, sqa, 0,0,0), B_col = (bx,by,bz, sqb, 1, 0,0,0)
// => MFMA dot = sqa + sqb - 2 a.b = full squared distance (from quantized coords).
//
// R13 vs R12: R11/R12 calibration says the sweep runs ~8x above its VALU
// floor at ~208 VALU instrs/iter (R11: VALUBusy 37% of 144K cyc / 128 iters)
// vs ~40 expected. Signature matches gfx950 AGPR marshaling (m98: compiler
// places MFMA C/D in AGPRs under pressure): 4 concurrent floatx16 d's = 64
// acc regs -> per iter 64 v_accvgpr_write (re-zero C) + 64 v_accvgpr_read
// (feed min3) = +128 VALU/iter. Fix: halve MFMA group width 4 -> 2
// (live d = 32 regs, total ~86 << 128 cap) so the allocator keeps C/D in
// VGPRs -- marshaling gone, min3 count per distance unchanged. Loop trip
// count is compile-time (NP bound to 16384) for scheduling/unroll.
// Macro-structure unchanged from R12: 2 dispatches (memset + fused kernel),
// full B cloud in 128KB LDS, BLK=1024 = 16 waves = 4/SIMD (proven TLP),
// waves = 4 row-groups x 4 B-quarters, no grid.sync (R10: ~100us/sync).

typedef _Float16 half8    __attribute__((ext_vector_type(8)));
typedef float    floatx16 __attribute__((ext_vector_type(16)));

constexpr int NPTS = 16384;    // padded cloud size (128 KB LDS), fixed problem
constexpr int ROWS = 128;      // A-rows per block (4 row-groups * 32)
constexpr int BLK  = 1024;     // 16 waves = 4/SIMD at 1 block/CU

// ---- pack one point into an f16 fragment (x,y,z,|p|^2) ----
__device__ __forceinline__ uint2 pack_point(const float* __restrict__ P, int j)
{
    float x = P[3*j], y = P[3*j+1], z = P[3*j+2];
    _Float16 hx = (_Float16)x, hy = (_Float16)y, hz = (_Float16)z;
    float qx = (float)hx, qy = (float)hy, qz = (float)hz;
    _Float16 hw = (_Float16)(qx*qx + qy*qy + qz*qz);
    union { _Float16 h[4]; uint2 u; } p;
    p.h[0] = hx; p.h[1] = hy; p.h[2] = hz; p.h[3] = hw;
    return p.u;
}

// One fused kernel: pack B->LDS, pack own A-rows->regs, sweep, reduce, atomicAdd.
__global__ __launch_bounds__(BLK, 4) void chamfer_all_kernel(
    const float* __restrict__ P1, const float* __restrict__ P2,
    float* __restrict__ out, int n1, int n2)
{
    __shared__ uint2 sB[NPTS];            // packed B cloud
    __shared__ float sRowMin[4][ROWS];    // per-B-quarter row mins
    __shared__ float sRed[ROWS];          // final per-row sqrt'd values

    const int dir   = blockIdx.z;
    const float* PA = dir == 0 ? P1 : P2;
    const float* PB = dir == 0 ? P2 : P1;
    const int nA    = dir == 0 ? n1 : n2;
    const int nB    = dir == 0 ? n2 : n1;

    const int tid  = threadIdx.x;
    const int wave = tid >> 6;
    const int lane = tid & 63;
    const int n    = lane & 31;
    const int g    = lane >> 5;
    const bool g0  = (g == 0);
    const int wr   = wave & 3;        // row-group: rows wr*32 .. wr*32+31
    const int wq   = wave >> 2;       // B-quarter index

    // ---- pack the FULL B cloud into LDS (reads are L2-resident, 192 KB) ----
    for (int j = tid; j < NPTS; j += BLK) {
        int jj = j < nB ? j : nB - 1;        // pad with dup of last point
        sB[j] = pack_point(PB, jj);
    }

    // ---- A fragment: pack own row directly from fp32 points ----
    const _Float16 h0 = (_Float16)0.0f;
    half8 af;
    {
        int arow = blockIdx.x * ROWS + wr * 32 + n;
        int j = arow < nA ? arow : nA - 1;
        union { uint2 u; _Float16 h[4]; } au; au.u = pack_point(PA, j);
        const _Float16 m2 = (_Float16)(-2.0f);
        af[0] = g0 ? (_Float16)(au.h[0] * m2) : h0;
        af[1] = g0 ? (_Float16)(au.h[1] * m2) : h0;
        af[2] = g0 ? (_Float16)(au.h[2] * m2) : h0;
        af[3] = g0 ? (_Float16)1.0f : h0;
        af[4] = g0 ? au.h[3] : h0;
        af[5] = h0; af[6] = h0; af[7] = h0;
    }

    __syncthreads();

    floatx16 rowmin;
#pragma unroll
    for (int r = 0; r < 16; ++r) rowmin[r] = 1e30f;
    const floatx16 zacc = {};

    // Persistent B-operand quads: upper pair (1.0h,0 | 0,0) written ONCE;
    // per-iter the prefetched uint2 lands in the lower pair.
    union BF { half8 v; unsigned u[4]; uint2 lo; };
    BF bu0, bu1;
    { union { _Float16 h[2]; unsigned u; } q;
      q.h[0] = (_Float16)1.0f; q.h[1] = h0;
      bu0.u[2] = q.u; bu0.u[3] = 0u;
      bu1.u[2] = q.u; bu1.u[3] = 0u; }

    // ---- sweep own B-quarter: 64 steps x (2 ds_read_b64 + 2 MFMA + 16 min3),
    //      1-step-ahead prefetch; 4 waves/SIMD provide latency hiding;
    //      live acc regs ~32 -> pure-VGPR allocation (no accvgpr marshaling) ----
    constexpr int QLEN = NPTS >> 2;            // 4096
    constexpr int NT   = QLEN / 64;            // 64 steps, compile-time
    const uint2* qbase = sB + wq * QLEN + n;   // g0/g1 broadcast same addr
    uint2 c0 = qbase[0], c1 = qbase[32];

    for (int bt = 0; bt < NT; ++bt) {
        const uint2* pn = qbase + (bt + 1 < NT ? (bt + 1) * 64 : 0);
        uint2 f0 = pn[0], f1 = pn[32];

        bu0.lo = c0;
        bu1.lo = c1;

        floatx16 d0 = __builtin_amdgcn_mfma_f32_32x32x16_f16(af, bu0.v, zacc, 0, 0, 0);
        floatx16 d1 = __builtin_amdgcn_mfma_f32_32x32x16_f16(af, bu1.v, zacc, 0, 0, 0);

#pragma unroll
        for (int r = 0; r < 16; ++r)
            rowmin[r] = fminf(fminf(rowmin[r], d0[r]), d1[r]);   // v_min3

        c0 = f0; c1 = f1;
    }

    // ---- reduce across the 32 cols (xor-shuffle within n-group) ----
#pragma unroll
    for (int mask = 1; mask <= 16; mask <<= 1)
#pragma unroll
        for (int r = 0; r < 16; ++r)
            rowmin[r] = fminf(rowmin[r], __shfl_xor(rowmin[r], mask));

    if (n == 0) {
#pragma unroll
        for (int r = 0; r < 16; ++r) {
            int rr = wr * 32 + g * 4 + ((r & 3) + 8 * (r >> 2));   // C/D row map
            sRowMin[wq][rr] = rowmin[r];
        }
    }
    __syncthreads();

    // ---- combine quarters, sqrt, block-sum, one atomicAdd ----
    if (tid < ROWS) {
        float m = fminf(fminf(sRowMin[0][tid], sRowMin[1][tid]),
                        fminf(sRowMin[2][tid], sRowMin[3][tid]));
        int grow = blockIdx.x * ROWS + tid;
        sRed[tid] = (grow < nA) ? sqrtf(fmaxf(m, 0.0f)) : 0.0f;
    }
    __syncthreads();

    if (tid < 64) {
        float v = sRed[tid] + sRed[tid + 64];
#pragma unroll
        for (int mask = 1; mask <= 32; mask <<= 1)
            v += __shfl_xor(v, mask);
        if (tid == 0) atomicAdd(out, v);
    }
}

extern "C" void kernel_launch(void* const* d_in, const int* in_sizes, int n_in,
                              void* d_out, int out_size, void* d_ws, size_t ws_size,
                              hipStream_t stream) {
    const float* P1 = (const float*)d_in[0];
    const float* P2 = (const float*)d_in[1];
    const int n1 = in_sizes[0] / 3;   // 16384
    const int n2 = in_sizes[1] / 3;   // 16384
    float* out = (float*)d_out;

    hipMemsetAsync(out, 0, sizeof(float), stream);   // capture-safe

    dim3 grid(NPTS / ROWS, 1, 2);                    // 256 blocks = exactly 1/CU
    chamfer_all_kernel<<<grid, BLK, 0, stream>>>(P1, P2, out, n1, n2);
}